// Round 10
// baseline (3157.016 us; speedup 1.0000x reference)
//
#include <hip/hip_runtime.h>

// ---------------------------------------------------------------------------
// StructureEncoder — naive verified fp32 pipeline, FP32 OUTPUT (d_out is
// float*: reference output dtype is fp32 per harness spec; earlier rounds
// wrote bf16 => garbage when read as fp32. Comparison tolerance is bf16-2%.)
// Edges: (2,E) int32 (harness converts int64 -> int32; detector keeps the
// int64-pairs path as a safety net).
// ---------------------------------------------------------------------------

__global__ void k_edetect(const int* __restrict__ ei, int n, int* __restrict__ flag) {
    if (threadIdx.x == 0 && blockIdx.x == 0) {
        int is64 = 1;
        for (int i = 0; i < 64; ++i) {
            if (ei[2 * i + 1] != 0 || (unsigned)ei[2 * i] >= (unsigned)n) { is64 = 0; break; }
        }
        *flag = is64;
    }
}

__global__ __launch_bounds__(256) void k_deg(const int* __restrict__ ei,
                                             const int* __restrict__ eflag,
                                             unsigned* __restrict__ deg, int e, int n) {
    int i = blockIdx.x * 256 + threadIdx.x;
    if (i >= e) return;
    int d = (*eflag) ? ei[2 * (size_t)e + 2 * (size_t)i] : ei[(size_t)e + i];
    if ((unsigned)d < (unsigned)n) atomicAdd(&deg[d], 1u);
}

__global__ __launch_bounds__(256) void k_dis(const unsigned* __restrict__ deg,
                                             float* __restrict__ dis, int n) {
    int i = blockIdx.x * 256 + threadIdx.x;
    if (i < n) dis[i] = rsqrtf((float)deg[i] + 1.0f);
}

// naive GEMM: out[r*J+j] = sum_k A[r*K+k] * W[k*J+j]
__global__ __launch_bounds__(256) void k_gemm(const float* __restrict__ A,
                                              const float* __restrict__ W,
                                              float* __restrict__ out,
                                              int nrows, int K, int J) {
    long long id = (long long)blockIdx.x * 256 + threadIdx.x;
    if (id >= (long long)nrows * J) return;
    int r = (int)(id / J), j = (int)(id % J);
    const float* a = A + (size_t)r * K;
    float acc = 0.f;
    for (int k = 0; k < K; ++k) acc = fmaf(a[k], W[(size_t)k * J + j], acc);
    out[id] = acc;
}

// per-edge scatter: one block (128 threads) per edge; fp32 atomics
__global__ __launch_bounds__(128) void k_scatter(const float* __restrict__ hW,
                                                 const int* __restrict__ ei,
                                                 const int* __restrict__ eflag,
                                                 const float* __restrict__ dis,
                                                 float* __restrict__ agg, int e, int n) {
    int edge = blockIdx.x, c = threadIdx.x;
    if (edge >= e) return;
    int s, d;
    if (*eflag) {
        s = ei[2 * (size_t)edge];
        d = ei[2 * (size_t)e + 2 * (size_t)edge];
    } else {
        s = ei[edge];
        d = ei[(size_t)e + edge];
    }
    if ((unsigned)s >= (unsigned)n || (unsigned)d >= (unsigned)n) return;
    float w = dis[s] * dis[d];
    atomicAdd(&agg[(size_t)d * 128 + c], hW[(size_t)s * 128 + c] * w);
}

// self-loop + conv bias: h[r][c] += hW[r][c]*dis[r]^2 + b[c]
__global__ __launch_bounds__(256) void k_selfbias(const float* __restrict__ hW,
                                                  const float* __restrict__ dis,
                                                  const float* __restrict__ b,
                                                  float* __restrict__ h, int n) {
    long long id = (long long)blockIdx.x * 256 + threadIdx.x;
    if (id >= (long long)n * 128) return;
    int r = (int)(id >> 7), c = (int)(id & 127);
    h[id] += hW[id] * dis[r] * dis[r] + b[c];
}

// exact per-channel BN stats: one block per channel
__global__ __launch_bounds__(256) void k_bnstat(const float* __restrict__ h,
                                                const float* __restrict__ g,
                                                const float* __restrict__ be,
                                                float* __restrict__ bnp, int n) {
    int c = blockIdx.x, t = threadIdx.x;
    float s = 0.f, s2 = 0.f;
    for (int r = t; r < n; r += 256) {
        float v = h[(size_t)r * 128 + c];
        s += v;
        s2 = fmaf(v, v, s2);
    }
    __shared__ float sa[256], sb[256];
    sa[t] = s; sb[t] = s2;
    __syncthreads();
    for (int o = 128; o > 0; o >>= 1) {
        if (t < o) { sa[t] += sa[t + o]; sb[t] += sb[t + o]; }
        __syncthreads();
    }
    if (t == 0) {
        float mean = sa[0] / (float)n;
        float var  = sb[0] / (float)n - mean * mean;
        float sc   = g[c] * rsqrtf(var + 1e-5f);
        bnp[c]       = sc;
        bnp[128 + c] = be[c] - mean * sc;
    }
}

__global__ __launch_bounds__(256) void k_bnrelu(const float* __restrict__ h,
                                                const float* __restrict__ bnp,
                                                float* __restrict__ out, int n) {
    long long id = (long long)blockIdx.x * 256 + threadIdx.x;
    if (id >= (long long)n * 128) return;
    int c = (int)(id & 127);
    out[id] = fmaxf(0.f, fmaf(h[id], bnp[c], bnp[128 + c]));
}

// head: out_fp32[r*64+j] = sum_k h[r*128+k]*W[k*64+j] + bias[j]
__global__ __launch_bounds__(256) void k_head(const float* __restrict__ h,
                                              const float* __restrict__ W,
                                              const float* __restrict__ bias,
                                              float* __restrict__ out, int nrows) {
    long long id = (long long)blockIdx.x * 256 + threadIdx.x;
    if (id >= (long long)nrows * 64) return;
    int r = (int)(id / 64), j = (int)(id % 64);
    const float* a = h + (size_t)r * 128;
    float acc = bias[j];
    for (int k = 0; k < 128; ++k) acc = fmaf(a[k], W[(size_t)k * 64 + j], acc);
    out[id] = acc;
}

// ---------------------------------------------------------------------------

extern "C" void kernel_launch(void* const* d_in, const int* in_sizes, int n_in,
                              void* d_out, int out_size, void* d_ws, size_t ws_size,
                              hipStream_t stream) {
    const float* x   = (const float*)d_in[0];
    const int*   ei  = (const int*)d_in[1];
    const float* W1  = (const float*)d_in[2];
    const float* b1  = (const float*)d_in[3];
    const float* g1  = (const float*)d_in[4];
    const float* be1 = (const float*)d_in[5];
    const float* W2  = (const float*)d_in[6];
    const float* b2  = (const float*)d_in[7];
    const float* g2  = (const float*)d_in[8];
    const float* be2 = (const float*)d_in[9];
    const float* Wmu = (const float*)d_in[10];
    const float* bmu = (const float*)d_in[11];
    const float* Wlv = (const float*)d_in[12];
    const float* blv = (const float*)d_in[13];

    const int n = in_sizes[0] / 128;   // 100000
    const int e = in_sizes[1] / 2;     // 1600000

    float* out = (float*)d_out;        // FP32 output: [mu (n*64) | logvar (n*64)]

    const size_t nbytes = (size_t)n * 128 * 4;
    char* ws = (char*)d_ws;
    size_t off = 0;
    auto alloc = [&](size_t bytes) {
        void* p = ws + off;
        off = (off + bytes + 255) & ~(size_t)255;
        return p;
    };
    float*    bufA  = (float*)alloc(nbytes);
    float*    bufB  = (float*)alloc(nbytes);
    unsigned* deg   = (unsigned*)alloc((size_t)n * 4);
    float*    dis   = (float*)alloc((size_t)n * 4);
    float*    bnp   = (float*)alloc(256 * 4);
    int*      eflag = (int*)alloc(256);

    const int eb  = (e + 255) / 256;
    const int nb1 = (n + 255) / 256;
    const int gNE = (int)(((long long)n * 128 + 255) / 256);
    const int gNH = (int)(((long long)n * 64 + 255) / 256);

    // graph preprocessing
    hipMemsetAsync(deg, 0, (size_t)n * 4, stream);
    k_edetect<<<1, 64, 0, stream>>>(ei, n, eflag);
    k_deg<<<eb, 256, 0, stream>>>(ei, eflag, deg, e, n);
    k_dis<<<nb1, 256, 0, stream>>>(deg, dis, n);

    // ---- layer 1 ----
    k_gemm<<<gNE, 256, 0, stream>>>(x, W1, bufA, n, 128, 128);
    hipMemsetAsync(bufB, 0, nbytes, stream);
    k_scatter<<<e, 128, 0, stream>>>(bufA, ei, eflag, dis, bufB, e, n);
    k_selfbias<<<gNE, 256, 0, stream>>>(bufA, dis, b1, bufB, n);
    k_bnstat<<<128, 256, 0, stream>>>(bufB, g1, be1, bnp, n);
    k_bnrelu<<<gNE, 256, 0, stream>>>(bufB, bnp, bufA, n);

    // ---- layer 2 ----
    k_gemm<<<gNE, 256, 0, stream>>>(bufA, W2, bufB, n, 128, 128);
    hipMemsetAsync(bufA, 0, nbytes, stream);
    k_scatter<<<e, 128, 0, stream>>>(bufB, ei, eflag, dis, bufA, e, n);
    k_selfbias<<<gNE, 256, 0, stream>>>(bufB, dis, b2, bufA, n);
    k_bnstat<<<128, 256, 0, stream>>>(bufA, g2, be2, bnp, n);
    k_bnrelu<<<gNE, 256, 0, stream>>>(bufA, bnp, bufB, n);

    // ---- heads (fp32 out: mu then logvar, concatenated) ----
    k_head<<<gNH, 256, 0, stream>>>(bufB, Wmu, bmu, out, n);
    k_head<<<gNH, 256, 0, stream>>>(bufB, Wlv, blv, out + (size_t)n * 64, n);
}